// Round 6
// baseline (862.133 us; speedup 1.0000x reference)
//
#include <hip/hip_runtime.h>
#include <hip/hip_bf16.h>
#include <cstdint>
#include <cstddef>

#define D_DIM 1024
#define VOCAB 32000
#define ROWS  4096      // 16*256

typedef __attribute__((ext_vector_type(8))) short bf16x8;   // 8 bf16 (MFMA A/B frag)
typedef __attribute__((ext_vector_type(4))) float f32x4;    // MFMA C/D frag
typedef __attribute__((ext_vector_type(4))) int   i32x4;    // 16B LDS/global move
typedef __attribute__((ext_vector_type(8))) int   i32x8;    // fp8 K=128 A/B frag (8 VGPRs)

static __device__ __forceinline__ i32x8 cat8(i32x4 lo, i32x4 hi) {
  return __builtin_shufflevector(lo, hi, 0, 1, 2, 3, 4, 5, 6, 7);
}

// float -> bf16 bits, round-to-nearest-even
static __device__ __forceinline__ unsigned short f2bf(float f) {
  union { float f; unsigned int u; } c; c.f = f;
  unsigned int u = c.u;
  u += 0x7fffu + ((u >> 16) & 1u);
  return (unsigned short)(u >> 16);
}

// pack two floats -> two fp8 e4m3 bytes (low 16 bits of result)
static __device__ __forceinline__ int pk8(float a, float b) {
  return __builtin_amdgcn_cvt_pk_fp8_f32(a, b, 0, false);
}

// async global->LDS, 16B per lane. LDS base wave-uniform; data lands at base + lane*16.
static __device__ __forceinline__ void gload_lds16(const void* g, void* s) {
  __builtin_amdgcn_global_load_lds(
      (const __attribute__((address_space(1))) uint32_t*)(g),
      (__attribute__((address_space(3))) uint32_t*)(s), 16, 0, 0);
}

// ---------------------------------------------------------------------------
// fp32 -> bf16 convert (4 elems/thread) — used for W only
__global__ void k_cvt(const float* __restrict__ src, short* __restrict__ dst, int n4) {
  int i = blockIdx.x * 256 + threadIdx.x;
  if (i < n4) {
    float4 v = *(const float4*)(src + (size_t)i * 4);
    ushort4 u;
    u.x = f2bf(v.x); u.y = f2bf(v.y); u.z = f2bf(v.z); u.w = f2bf(v.w);
    *(ushort4*)(dst + (size_t)i * 4) = u;
  }
}

// ---------------------------------------------------------------------------
// patch fp32 -> Q fp8 e4m3 (unscaled; |patch| ~ N(0,1) fits), 8 elems/thread
__global__ void k_cvt_q8(const float* __restrict__ src, uint8_t* __restrict__ dst) {
  int i = blockIdx.x * 256 + threadIdx.x;
  float4 a = *(const float4*)(src + (size_t)i * 8);
  float4 b = *(const float4*)(src + (size_t)i * 8 + 4);
  uint2 o;
  o.x = (pk8(a.x, a.y) & 0xffff) | (pk8(a.z, a.w) << 16);
  o.y = (pk8(b.x, b.y) & 0xffff) | (pk8(b.z, b.w) << 16);
  *(uint2*)(dst + (size_t)i * 8) = o;
}

// ---------------------------------------------------------------------------
// fused: proto fp32 [R][C] -> Kb fp8 [R][C] (x64) AND KT fp8 [C][R] (x64), one read
__global__ void k_prep_K8(const float* __restrict__ src, uint8_t* __restrict__ kb,
                          uint8_t* __restrict__ kt, int R, int C) {
  __shared__ uint8_t tile[64][68];
  int t  = threadIdx.x;           // 0..255
  int r0 = blockIdx.x * 64;       // v block
  int c0 = blockIdx.y * 64;       // d block
  int lr = t >> 4;                // 0..15
  int lc = (t & 15) * 4;          // 0..60
#pragma unroll
  for (int i = 0; i < 4; ++i) {
    int r = lr + 16 * i;
    float4 v = *(const float4*)(src + (size_t)(r0 + r) * C + c0 + lc);
    unsigned p = (pk8(v.x * 64.f, v.y * 64.f) & 0xffff) | (pk8(v.z * 64.f, v.w * 64.f) << 16);
    *(unsigned*)&tile[r][lc] = p;
    *(unsigned*)(kb + (size_t)(r0 + r) * C + c0 + lc) = p;
  }
  __syncthreads();
#pragma unroll
  for (int i = 0; i < 4; ++i) {
    int c = lr + 16 * i;          // d within tile
    unsigned p = tile[lc + 0][c] | (tile[lc + 1][c] << 8) |
                 (tile[lc + 2][c] << 16) | ((unsigned)tile[lc + 3][c] << 24);
    *(unsigned*)(kt + (size_t)(c0 + c) * R + r0 + lc) = p;
  }
}

// ---------------------------------------------------------------------------
// GEMM1: P = exp(Q @ K^T) (x64 scale), den += rowsum.
// M=4096 N=32000 K=1024, fp8 MX. ROUND-6 STRUCTURE (cut LDS instrs/FLOP):
//   256(m) x 256(n) tile, 512 thr = 8 waves (4M x 2N), 64x128 PER WAVE.
//   Per wave per K-step: 24 ds_read_b128 feed 32 MFMAs (was 16 per 16 —
//   25% fewer LDS-port cycles per FLOP; staging bytes/FLOP halved).
//   VGPR: acc 32xf32x4=128 + bf[8]=64 + am=8 -> ~230, 2 waves/SIMD.
//   2-slot ring (2 x 64KB), round-4-proven double-barrier + counted vmcnt(8):
//     { vmcnt(8)+barrier; frag reads + MFMA; barrier; STAGE(t+2) }
// Grid 2000 = 8 x 250 XCD-chunked (each XCD: 16 n-panels + all of Q in L2).
// P stored NON-TEMPORAL (plain stores write-allocate-evict L2; round-3 data).
#define PS1 272    // P-tile LDS row stride, bytes (16B-aligned, 256+16)
#define G1NT 8     // 1024/128 K-steps
__global__ __launch_bounds__(512, 2) void k_g1(
    const uint8_t* __restrict__ A,      // Q8 [4096][1024]
    const uint8_t* __restrict__ B,      // Kb8 [32000][1024]
    uint8_t* __restrict__ Pout, float* __restrict__ den)
{
  __shared__ uint8_t smem[131072];      // 2 slots x (A 32KB + B 32KB)

  int tid  = threadIdx.x;
  int wave = tid >> 6;                  // 0..7
  int lane = tid & 63;
  int quad = lane >> 4;
  int t16  = lane & 15;
  int wm = wave >> 1;                   // 0..3 (M, 64 rows each)
  int wn = wave & 1;                    // 0..1 (N, 128 cols each)

  int swz = (blockIdx.x & 7) * 250 + (blockIdx.x >> 3);  // bijective, 2000=8*250
  int nt  = swz >> 4;                   // 0..124  n-tile (256 vocab cols)
  int mt  = swz & 15;                   // 0..15   m-tile (256 rows)
  long mBase = (long)mt * 256;
  long nBase = (long)nt * 256;

  const uint8_t* Ab = A + (size_t)mBase * D_DIM;
  const uint8_t* Bb = B + (size_t)nBase * D_DIM;
  int lrow = lane >> 3;                      // 0..7
  int lcol = ((lane & 7) ^ lrow) * 16;       // swizzled source 16B chunk (bytes)

  f32x4 acc[4][8];
#pragma unroll
  for (int i = 0; i < 4; ++i)
#pragma unroll
    for (int j = 0; j < 8; ++j) acc[i][j] = (f32x4){0.f, 0.f, 0.f, 0.f};

  int sw  = t16 & 7;
  int co0 = (((quad << 1) ^ sw) << 4);
  const int SC1 = 0x7F7F7F7F;                // identity E8M0 scales

  // stage K-step t into slot: A 32KB + B 32KB, 4+4 gloads/wave (vmcnt unit: 8)
  auto STAGE = [&](int slot, int t) {
    uint8_t* As = &smem[slot * 65536];
    uint8_t* Bs = As + 32768;
    int kk = t * 128;
#pragma unroll
    for (int g = 0; g < 4; ++g) {
      int r0 = wave * 32 + g * 8;
      gload_lds16(Ab + (size_t)(r0 + lrow) * D_DIM + kk + lcol, As + r0 * 128);
    }
#pragma unroll
    for (int g = 0; g < 4; ++g) {
      int r0 = wave * 32 + g * 8;
      gload_lds16(Bb + (size_t)(r0 + lrow) * D_DIM + kk + lcol, Bs + r0 * 128);
    }
  };

  STAGE(0, 0);
  STAGE(1, 1);                          // 16 loads in flight per wave

  for (int t = 0; t < G1NT; ++t) {
    if (t + 1 < G1NT)
      asm volatile("s_waitcnt vmcnt(8)\n\ts_barrier" ::: "memory");
    else
      asm volatile("s_waitcnt vmcnt(0)\n\ts_barrier" ::: "memory");

    const uint8_t* As = &smem[(t & 1) * 65536];
    const uint8_t* Bs = As + 32768;

    i32x8 bf[8];
#pragma unroll
    for (int ni = 0; ni < 8; ++ni) {
      const uint8_t* rp = &Bs[(wn * 128 + ni * 16 + t16) * 128];
      bf[ni] = cat8(*(const i32x4*)(rp + co0), *(const i32x4*)(rp + (co0 ^ 16)));
    }
    __builtin_amdgcn_s_setprio(1);
#pragma unroll
    for (int mi = 0; mi < 4; ++mi) {
      const uint8_t* rp = &As[(wm * 64 + mi * 16 + t16) * 128];
      i32x8 am = cat8(*(const i32x4*)(rp + co0), *(const i32x4*)(rp + (co0 ^ 16)));
#pragma unroll
      for (int ni = 0; ni < 8; ++ni)
        acc[mi][ni] = __builtin_amdgcn_mfma_scale_f32_16x16x128_f8f6f4(
            am, bf[ni], acc[mi][ni], 0, 0, 0, SC1, 0, SC1);
    }
    __builtin_amdgcn_s_setprio(0);
    asm volatile("s_barrier" ::: "memory");
    if (t + 2 < G1NT) STAGE(t & 1, t + 2);
  }

  // ---- epilogue: e = exp(acc/64) -> fp8 P-tile in LDS; den += rowsum ----
  float rsum[4][4];
#pragma unroll
  for (int mi = 0; mi < 4; ++mi)
#pragma unroll
    for (int r = 0; r < 4; ++r) rsum[mi][r] = 0.f;
#pragma unroll
  for (int mi = 0; mi < 4; ++mi) {
    int rloc = wm * 64 + mi * 16 + quad * 4;
#pragma unroll
    for (int ni = 0; ni < 8; ++ni) {
      int cloc = wn * 128 + ni * 16 + t16;
#pragma unroll
      for (int r = 0; r < 4; ++r) {
        float e = __expf(acc[mi][ni][r] * 0.015625f);   // undo K x64 scale
        smem[(rloc + r) * PS1 + cloc] = (uint8_t)pk8(e, e);
        rsum[mi][r] += e;
      }
    }
  }
#pragma unroll
  for (int mi = 0; mi < 4; ++mi)
#pragma unroll
    for (int r = 0; r < 4; ++r) {
      float s = rsum[mi][r];
      s += __shfl_xor(s, 1);
      s += __shfl_xor(s, 2);
      s += __shfl_xor(s, 4);
      s += __shfl_xor(s, 8);
      if (t16 == 0)
        atomicAdd(&den[mBase + wm * 64 + mi * 16 + quad * 4 + r], s);
    }
  __syncthreads();
  // coalesced NT store: 8 x 512thr x 16B = 64KB fp8 tile (256 x 256)
  int rr  = tid >> 4;            // 0..31
  int c16 = (tid & 15) * 16;     // 0..240
#pragma unroll
  for (int i = 0; i < 8; ++i) {
    int row = i * 32 + rr;
    i32x4 v = *(const i32x4*)&smem[row * PS1 + c16];
    __builtin_nontemporal_store(v, (i32x4*)&Pout[(size_t)(mBase + row) * VOCAB + nBase + c16]);
  }
}

// ---------------------------------------------------------------------------
// GEMM2: num[m][d] = P @ K, M=4096 N=1024 K=32000. Same 256x256 / 64x128-wave
// structure. z=5 K-split (6400 = 50 K-steps each), grid 320 = z(hi) x m x d.
// Slices: z{0,3}->s0 (atomicAdd, zero-init), z{1,4}->s1 (atomicAdd), z2->s2
// (plain) — s0/s1 live in Q8+Kb8 (dead after g1; memset enqueued AFTER g1),
// s2 = num. No new workspace. k_div sums the 3 slices.
#define G2NT 50    // 6400/128 K-steps per z-slice
__global__ __launch_bounds__(512, 2) void k_g2(
    const uint8_t* __restrict__ P, const uint8_t* __restrict__ KT,
    float* __restrict__ s0, float* __restrict__ s1, float* __restrict__ s2)
{
  __shared__ uint8_t smem[131072];      // 2 slots x (A 32KB + B 32KB)

  int tid  = threadIdx.x;
  int wave = tid >> 6;
  int lane = tid & 63;
  int quad = lane >> 4;
  int t16  = lane & 15;
  int wm = wave >> 1;                   // 0..3 (M)
  int wn = wave & 1;                    // 0..1 (D)

  int bid = blockIdx.x;
  int dt  = bid & 3;                    // 0..3  d-tile (256 cols)
  int mt  = (bid >> 2) & 15;            // 0..15 m-tile (256 rows)
  int zz  = bid >> 6;                   // 0..4  K-slice
  long mBase = (long)mt * 256;
  long dBase = (long)dt * 256;
  int  k0    = zz * 6400;

  const uint8_t* Ab = P  + (size_t)mBase * VOCAB + k0;
  const uint8_t* Bb = KT + (size_t)dBase * VOCAB + k0;
  int lrow = lane >> 3;
  int lcol = ((lane & 7) ^ lrow) * 16;

  f32x4 acc[4][8];
#pragma unroll
  for (int i = 0; i < 4; ++i)
#pragma unroll
    for (int j = 0; j < 8; ++j) acc[i][j] = (f32x4){0.f, 0.f, 0.f, 0.f};

  int sw  = t16 & 7;
  int co0 = (((quad << 1) ^ sw) << 4);
  const int SC1 = 0x7F7F7F7F;

  auto STAGE = [&](int slot, int t) {
    uint8_t* As = &smem[slot * 65536];
    uint8_t* Bs = As + 32768;
    long kk = (long)t * 128;
#pragma unroll
    for (int g = 0; g < 4; ++g) {
      int r0 = wave * 32 + g * 8;
      gload_lds16(Ab + (size_t)(r0 + lrow) * VOCAB + kk + lcol, As + r0 * 128);
    }
#pragma unroll
    for (int g = 0; g < 4; ++g) {
      int r0 = wave * 32 + g * 8;
      gload_lds16(Bb + (size_t)(r0 + lrow) * VOCAB + kk + lcol, Bs + r0 * 128);
    }
  };

  STAGE(0, 0);
  STAGE(1, 1);                          // 16 loads in flight per wave

  for (int t = 0; t < G2NT; ++t) {
    if (t + 1 < G2NT)
      asm volatile("s_waitcnt vmcnt(8)\n\ts_barrier" ::: "memory");
    else
      asm volatile("s_waitcnt vmcnt(0)\n\ts_barrier" ::: "memory");

    const uint8_t* As = &smem[(t & 1) * 65536];
    const uint8_t* Bs = As + 32768;

    i32x8 bf[8];
#pragma unroll
    for (int ni = 0; ni < 8; ++ni) {
      const uint8_t* rp = &Bs[(wn * 128 + ni * 16 + t16) * 128];
      bf[ni] = cat8(*(const i32x4*)(rp + co0), *(const i32x4*)(rp + (co0 ^ 16)));
    }
    __builtin_amdgcn_s_setprio(1);
#pragma unroll
    for (int mi = 0; mi < 4; ++mi) {
      const uint8_t* rp = &As[(wm * 64 + mi * 16 + t16) * 128];
      i32x8 am = cat8(*(const i32x4*)(rp + co0), *(const i32x4*)(rp + (co0 ^ 16)));
#pragma unroll
      for (int ni = 0; ni < 8; ++ni)
        acc[mi][ni] = __builtin_amdgcn_mfma_scale_f32_16x16x128_f8f6f4(
            am, bf[ni], acc[mi][ni], 0, 0, 0, SC1, 0, SC1);
    }
    __builtin_amdgcn_s_setprio(0);
    asm volatile("s_barrier" ::: "memory");
    if (t + 2 < G2NT) STAGE(t & 1, t + 2);
  }

  // epilogue: z2 plain-stores its slice; others atomicAdd (2 writers/slice)
  float* outp = (zz == 2) ? s2 : ((zz == 0 || zz == 3) ? s0 : s1);
  bool plain = (zz == 2);
#pragma unroll
  for (int mi = 0; mi < 4; ++mi) {
    long row = mBase + wm * 64 + mi * 16 + quad * 4;
#pragma unroll
    for (int ni = 0; ni < 8; ++ni) {
      long col = dBase + wn * 128 + ni * 16 + t16;
#pragma unroll
      for (int r = 0; r < 4; ++r) {
        float* p = &outp[(size_t)(row + r) * D_DIM + col];
        if (plain) *p = acc[mi][ni][r];
        else       atomicAdd(p, acc[mi][ni][r]);
      }
    }
  }
}

// ---------------------------------------------------------------------------
// bf16 GEMM for GEMM3 only: Cout = A@B^T + bias[col] + resid (128x128 tile, BK=64)
__global__ __launch_bounds__(256) void k_gemm_bf(
    const short* __restrict__ A, int lda,
    const short* __restrict__ B, int ldb, int Kdim,
    const float* __restrict__ bias, const float* __restrict__ resid,
    float* __restrict__ Cout)
{
  __shared__ short smem[16384];
  short* As = smem;
  short* Bs = smem + 8192;

  int tid  = threadIdx.x;
  int wave = tid >> 6;
  int lane = tid & 63;
  int quad = lane >> 4;
  int t16  = lane & 15;
  int wy = wave >> 1, wx = wave & 1;

  long mBase = (long)blockIdx.y * 128;
  long nBase = (long)blockIdx.x * 128;

  const short* Ab = A + (size_t)mBase * lda;
  const short* Bb = B + (size_t)nBase * ldb;
  int lrow = lane >> 3;
  int lcol = ((lane & 7) ^ lrow) * 8;

  f32x4 acc[4][4];
#pragma unroll
  for (int i = 0; i < 4; ++i)
#pragma unroll
    for (int j = 0; j < 4; ++j) acc[i][j] = (f32x4){0.f, 0.f, 0.f, 0.f};

  int sw = t16 & 7;

  for (int kk = 0; kk < Kdim; kk += 64) {
#pragma unroll
    for (int i = 0; i < 4; ++i) {
      int row = wave * 32 + i * 8;
      gload_lds16(Ab + (size_t)(row + lrow) * lda + kk + lcol, &As[row * 64]);
      gload_lds16(Bb + (size_t)(row + lrow) * ldb + kk + lcol, &Bs[row * 64]);
    }
    __syncthreads();
#pragma unroll
    for (int kc = 0; kc < 8; kc += 4) {
      bf16x8 af[4], bfr[4];
#pragma unroll
      for (int mi = 0; mi < 4; ++mi)
        af[mi] = *(const bf16x8*)&As[(wy * 64 + mi * 16 + t16) * 64 +
                                     (((kc + quad) ^ sw) << 3)];
#pragma unroll
      for (int ni = 0; ni < 4; ++ni)
        bfr[ni] = *(const bf16x8*)&Bs[(wx * 64 + ni * 16 + t16) * 64 +
                                      (((kc + quad) ^ sw) << 3)];
#pragma unroll
      for (int mi = 0; mi < 4; ++mi)
#pragma unroll
        for (int ni = 0; ni < 4; ++ni)
          acc[mi][ni] = __builtin_amdgcn_mfma_f32_16x16x32_bf16(af[mi], bfr[ni],
                                                                acc[mi][ni], 0, 0, 0);
    }
    __syncthreads();
  }

#pragma unroll
  for (int mi = 0; mi < 4; ++mi) {
    long row = mBase + wy * 64 + mi * 16 + quad * 4;
#pragma unroll
    for (int ni = 0; ni < 4; ++ni) {
      long col = nBase + wx * 64 + ni * 16 + t16;
#pragma unroll
      for (int r = 0; r < 4; ++r) {
        size_t idx = (size_t)(row + r) * 1024 + col;
        Cout[idx] = acc[mi][ni][r] + bias[col] + resid[idx];
      }
    }
  }
}

// ---------------------------------------------------------------------------
// reprog_bf16 = bf16((s0+s1+s2) / (64*den[row]))  (undo K x64 scale, sum slices)
__global__ void k_div(const float* __restrict__ s0, const float* __restrict__ s1,
                      const float* __restrict__ s2,
                      const float* __restrict__ den, short* __restrict__ out) {
  int i = (blockIdx.x * 256 + threadIdx.x) * 4;
  float4 a = *(const float4*)(s0 + i);
  float4 b = *(const float4*)(s1 + i);
  float4 c = *(const float4*)(s2 + i);
  float inv = 0.015625f / den[i >> 10];
  ushort4 u;
  u.x = f2bf((a.x + b.x + c.x) * inv); u.y = f2bf((a.y + b.y + c.y) * inv);
  u.z = f2bf((a.z + b.z + c.z) * inv); u.w = f2bf((a.w + b.w + c.w) * inv);
  *(ushort4*)(out + i) = u;
}

// ---------------------------------------------------------------------------
// per-row LayerNorm over 1024 cols; one block (256 thr) per row
__global__ __launch_bounds__(256) void k_ln(const float* __restrict__ x,
                                            const float* __restrict__ gamma,
                                            const float* __restrict__ beta,
                                            float* __restrict__ out) {
  __shared__ float s_sum[4], s_sq[4];
  int row = blockIdx.x;
  int tid = threadIdx.x;
  const float* xr = x + (size_t)row * 1024;
  float4 v = *(const float4*)(xr + tid * 4);
  float s = v.x + v.y + v.z + v.w;
  float q = v.x * v.x + v.y * v.y + v.z * v.z + v.w * v.w;
#pragma unroll
  for (int off = 32; off >= 1; off >>= 1) {
    s += __shfl_down(s, off);
    q += __shfl_down(q, off);
  }
  int wv = tid >> 6;
  if ((tid & 63) == 0) { s_sum[wv] = s; s_sq[wv] = q; }
  __syncthreads();
  float tot  = s_sum[0] + s_sum[1] + s_sum[2] + s_sum[3];
  float totq = s_sq[0] + s_sq[1] + s_sq[2] + s_sq[3];
  float mu   = tot * (1.0f / 1024.0f);
  float var  = totq * (1.0f / 1024.0f) - mu * mu;
  float rstd = rsqrtf(var + 1e-5f);
  float4 g = *(const float4*)(gamma + tid * 4);
  float4 b = *(const float4*)(beta + tid * 4);
  float4 o;
  o.x = (v.x - mu) * rstd * g.x + b.x;
  o.y = (v.y - mu) * rstd * g.y + b.y;
  o.z = (v.z - mu) * rstd * g.z + b.z;
  o.w = (v.w - mu) * rstd * g.w + b.w;
  *(float4*)(out + (size_t)row * 1024 + tid * 4) = o;
}

// ---------------------------------------------------------------------------
extern "C" void kernel_launch(void* const* d_in, const int* in_sizes, int n_in,
                              void* d_out, int out_size, void* d_ws, size_t ws_size,
                              hipStream_t stream) {
  const float* patch = (const float*)d_in[0];   // [4096,1024]
  const float* proto = (const float*)d_in[1];   // [32000,1024]
  const float* W     = (const float*)d_in[2];   // [1024,1024]
  const float* bvec  = (const float*)d_in[3];
  const float* gamma = (const float*)d_in[4];
  const float* beta  = (const float*)d_in[5];
  float* out = (float*)d_out;

  char* ws = (char*)d_ws;
  size_t off = 0;
  uint8_t* Q8  = (uint8_t*)(ws + off); off += (size_t)ROWS * D_DIM;      //   4 MB fp8 Q
  uint8_t* Kb8 = (uint8_t*)(ws + off); off += (size_t)VOCAB * D_DIM;     //  31.25 MB fp8 K (x64)
  uint8_t* KT8 = (uint8_t*)(ws + off); off += (size_t)VOCAB * D_DIM;     //  31.25 MB fp8 K^T (x64)
  short*   Wb  = (short*)(ws + off);   off += (size_t)D_DIM * D_DIM * 2; //   2 MB bf16 W
  short*   Rb  = (short*)(ws + off);   off += (size_t)ROWS * D_DIM * 2;  //   8 MB bf16 reprog
  uint8_t* P8  = (uint8_t*)(ws + off); off += (size_t)ROWS * VOCAB;      // 131 MB fp8 P
  float*   num = (float*)(ws + off);   off += (size_t)ROWS * D_DIM * 4;  //  16 MB fp32
  float*   den = (float*)(ws + off);   off += (size_t)ROWS * 4;          //  16 KB fp32 den
  float*   pre = (float*)P8;    // reuse P region for pre-LN buffer (k_g2 done reading)
  // GEMM2 z=5 split slices: s0 @ ws+0 (16MB over Q8+Kb8-head), s1 @ ws+16MB
  // (Kb8 tail, ends at 32MB < 35.25MB KT8 start). Both dead after g1; the
  // zeroing memset is enqueued AFTER k_g1 on-stream. s2 = num (plain-stored).
  float*   sz0 = (float*)(ws);
  float*   sz1 = (float*)(ws + (size_t)16 * 1024 * 1024);
  float*   sz2 = num;

  hipMemsetAsync(den, 0, ROWS * sizeof(float), stream);

  k_cvt_q8<<<ROWS * D_DIM / 8 / 256, 256, 0, stream>>>(patch, Q8);
  k_cvt<<<D_DIM * D_DIM / 4 / 256, 256, 0, stream>>>(W, Wb, D_DIM * D_DIM / 4);
  k_prep_K8<<<dim3(VOCAB / 64, D_DIM / 64), 256, 0, stream>>>(proto, Kb8, KT8, VOCAB, D_DIM);

  // GEMM1: P = exp(Q @ K^T), den += rowsum — 256x256 tile, 64x128/wave
  k_g1<<<2000, 512, 0, stream>>>(Q8, Kb8, P8, den);

  // zero the atomic split-K slices (overwrites Q8/Kb8 — AFTER g1 on-stream)
  hipMemsetAsync(sz0, 0, (size_t)32 * 1024 * 1024, stream);

  // GEMM2: P @ K — 256x256 tile, 64x128/wave, z=5 (50 K-steps each)
  k_g2<<<320, 512, 0, stream>>>(P8, KT8, sz0, sz1, sz2);

  k_div<<<ROWS * D_DIM / 4 / 256, 256, 0, stream>>>(sz0, sz1, sz2, den, Rb);

  // GEMM3: pre = reprog @ W^T + b + patch — M=4096 N=1024 K=1024 (bf16)
  k_gemm_bf<<<dim3(D_DIM / 128, ROWS / 128), 256, 0, stream>>>(
      Rb, D_DIM, Wb, D_DIM, D_DIM, bvec, patch, pre);

  k_ln<<<ROWS, 256, 0, stream>>>(pre, gamma, beta, out);
}

// Round 7
// 723.189 us; speedup vs baseline: 1.1921x; 1.1921x over previous
//
#include <hip/hip_runtime.h>
#include <hip/hip_bf16.h>
#include <cstdint>
#include <cstddef>

#define D_DIM 1024
#define VOCAB 32000
#define ROWS  4096      // 16*256

typedef __attribute__((ext_vector_type(8))) short bf16x8;   // 8 bf16 (MFMA A/B frag)
typedef __attribute__((ext_vector_type(4))) float f32x4;    // MFMA C/D frag
typedef __attribute__((ext_vector_type(4))) int   i32x4;    // 16B LDS/global move
typedef __attribute__((ext_vector_type(8))) int   i32x8;    // fp8 K=128 A/B frag (8 VGPRs)

static __device__ __forceinline__ i32x8 cat8(i32x4 lo, i32x4 hi) {
  return __builtin_shufflevector(lo, hi, 0, 1, 2, 3, 4, 5, 6, 7);
}

// float -> bf16 bits, round-to-nearest-even
static __device__ __forceinline__ unsigned short f2bf(float f) {
  union { float f; unsigned int u; } c; c.f = f;
  unsigned int u = c.u;
  u += 0x7fffu + ((u >> 16) & 1u);
  return (unsigned short)(u >> 16);
}

// pack two floats -> two fp8 e4m3 bytes (low 16 bits of result)
static __device__ __forceinline__ int pk8(float a, float b) {
  return __builtin_amdgcn_cvt_pk_fp8_f32(a, b, 0, false);
}

// async global->LDS, 16B per lane. LDS base wave-uniform; data lands at base + lane*16.
static __device__ __forceinline__ void gload_lds16(const void* g, void* s) {
  __builtin_amdgcn_global_load_lds(
      (const __attribute__((address_space(1))) uint32_t*)(g),
      (__attribute__((address_space(3))) uint32_t*)(s), 16, 0, 0);
}

// ---------------------------------------------------------------------------
// fp32 -> bf16 convert (4 elems/thread) — used for W only
__global__ void k_cvt(const float* __restrict__ src, short* __restrict__ dst, int n4) {
  int i = blockIdx.x * 256 + threadIdx.x;
  if (i < n4) {
    float4 v = *(const float4*)(src + (size_t)i * 4);
    ushort4 u;
    u.x = f2bf(v.x); u.y = f2bf(v.y); u.z = f2bf(v.z); u.w = f2bf(v.w);
    *(ushort4*)(dst + (size_t)i * 4) = u;
  }
}

// ---------------------------------------------------------------------------
// patch fp32 -> Q fp8 e4m3 (unscaled; |patch| ~ N(0,1) fits), 8 elems/thread
__global__ void k_cvt_q8(const float* __restrict__ src, uint8_t* __restrict__ dst) {
  int i = blockIdx.x * 256 + threadIdx.x;
  float4 a = *(const float4*)(src + (size_t)i * 8);
  float4 b = *(const float4*)(src + (size_t)i * 8 + 4);
  uint2 o;
  o.x = (pk8(a.x, a.y) & 0xffff) | (pk8(a.z, a.w) << 16);
  o.y = (pk8(b.x, b.y) & 0xffff) | (pk8(b.z, b.w) << 16);
  *(uint2*)(dst + (size_t)i * 8) = o;
}

// ---------------------------------------------------------------------------
// fused: proto fp32 [R][C] -> Kb fp8 [R][C] (x64) AND KT fp8 [C][R] (x64), one read
__global__ void k_prep_K8(const float* __restrict__ src, uint8_t* __restrict__ kb,
                          uint8_t* __restrict__ kt, int R, int C) {
  __shared__ uint8_t tile[64][68];
  int t  = threadIdx.x;           // 0..255
  int r0 = blockIdx.x * 64;       // v block
  int c0 = blockIdx.y * 64;       // d block
  int lr = t >> 4;                // 0..15
  int lc = (t & 15) * 4;          // 0..60
#pragma unroll
  for (int i = 0; i < 4; ++i) {
    int r = lr + 16 * i;
    float4 v = *(const float4*)(src + (size_t)(r0 + r) * C + c0 + lc);
    unsigned p = (pk8(v.x * 64.f, v.y * 64.f) & 0xffff) | (pk8(v.z * 64.f, v.w * 64.f) << 16);
    *(unsigned*)&tile[r][lc] = p;
    *(unsigned*)(kb + (size_t)(r0 + r) * C + c0 + lc) = p;
  }
  __syncthreads();
#pragma unroll
  for (int i = 0; i < 4; ++i) {
    int c = lr + 16 * i;          // d within tile
    unsigned p = tile[lc + 0][c] | (tile[lc + 1][c] << 8) |
                 (tile[lc + 2][c] << 16) | ((unsigned)tile[lc + 3][c] << 24);
    *(unsigned*)(kt + (size_t)(c0 + c) * R + r0 + lc) = p;
  }
}

// ---------------------------------------------------------------------------
// GEMM1: P = exp(Q @ K^T) (x64 scale), den += rowsum.
// M=4096 N=32000 K=1024, fp8 MX. 256(m) x 256(n) tile, 512 thr = 8 waves
// (4M x 2N), 64x128 per wave: 24 ds_read_b128 feed 32 MFMAs per K-step.
// VGPR need ~220 (acc 128 + bf 64 + am/addr) -> __launch_bounds__(512,1)
// so hipcc can allocate up to 256 (round-6's (512,2) capped at 128 and
// SPILLED: WRITE_SIZE 160->425MB, the whole regression).
// LDS 128KB -> 1 block/CU, 2 waves/SIMD regardless; (512,1) costs nothing.
// 2-slot ring, counted vmcnt(8): { vmcnt(8)+barrier; reads+MFMA; barrier;
// STAGE(t+2) }. Grid 2000 = 8 x 250 XCD-chunked. P stored NON-TEMPORAL.
#define PS1 272    // P-tile LDS row stride, bytes (16B-aligned, 256+16)
#define G1NT 8     // 1024/128 K-steps
__global__ __launch_bounds__(512, 1) void k_g1(
    const uint8_t* __restrict__ A,      // Q8 [4096][1024]
    const uint8_t* __restrict__ B,      // Kb8 [32000][1024]
    uint8_t* __restrict__ Pout, float* __restrict__ den)
{
  __shared__ uint8_t smem[131072];      // 2 slots x (A 32KB + B 32KB)

  int tid  = threadIdx.x;
  int wave = tid >> 6;                  // 0..7
  int lane = tid & 63;
  int quad = lane >> 4;
  int t16  = lane & 15;
  int wm = wave >> 1;                   // 0..3 (M, 64 rows each)
  int wn = wave & 1;                    // 0..1 (N, 128 cols each)

  int swz = (blockIdx.x & 7) * 250 + (blockIdx.x >> 3);  // bijective, 2000=8*250
  int nt  = swz >> 4;                   // 0..124  n-tile (256 vocab cols)
  int mt  = swz & 15;                   // 0..15   m-tile (256 rows)
  long mBase = (long)mt * 256;
  long nBase = (long)nt * 256;

  const uint8_t* Ab = A + (size_t)mBase * D_DIM;
  const uint8_t* Bb = B + (size_t)nBase * D_DIM;
  int lrow = lane >> 3;                      // 0..7
  int lcol = ((lane & 7) ^ lrow) * 16;       // swizzled source 16B chunk (bytes)

  f32x4 acc[4][8];
#pragma unroll
  for (int i = 0; i < 4; ++i)
#pragma unroll
    for (int j = 0; j < 8; ++j) acc[i][j] = (f32x4){0.f, 0.f, 0.f, 0.f};

  int sw  = t16 & 7;
  int co0 = (((quad << 1) ^ sw) << 4);
  const int SC1 = 0x7F7F7F7F;                // identity E8M0 scales

  // stage K-step t into slot: A 32KB + B 32KB, 4+4 gloads/wave (vmcnt unit: 8)
  auto STAGE = [&](int slot, int t) {
    uint8_t* As = &smem[slot * 65536];
    uint8_t* Bs = As + 32768;
    int kk = t * 128;
#pragma unroll
    for (int g = 0; g < 4; ++g) {
      int r0 = wave * 32 + g * 8;
      gload_lds16(Ab + (size_t)(r0 + lrow) * D_DIM + kk + lcol, As + r0 * 128);
    }
#pragma unroll
    for (int g = 0; g < 4; ++g) {
      int r0 = wave * 32 + g * 8;
      gload_lds16(Bb + (size_t)(r0 + lrow) * D_DIM + kk + lcol, Bs + r0 * 128);
    }
  };

  STAGE(0, 0);
  STAGE(1, 1);                          // 16 loads in flight per wave

  for (int t = 0; t < G1NT; ++t) {
    if (t + 1 < G1NT)
      asm volatile("s_waitcnt vmcnt(8)\n\ts_barrier" ::: "memory");
    else
      asm volatile("s_waitcnt vmcnt(0)\n\ts_barrier" ::: "memory");

    const uint8_t* As = &smem[(t & 1) * 65536];
    const uint8_t* Bs = As + 32768;

    i32x8 bf[8];
#pragma unroll
    for (int ni = 0; ni < 8; ++ni) {
      const uint8_t* rp = &Bs[(wn * 128 + ni * 16 + t16) * 128];
      bf[ni] = cat8(*(const i32x4*)(rp + co0), *(const i32x4*)(rp + (co0 ^ 16)));
    }
    __builtin_amdgcn_s_setprio(1);
#pragma unroll
    for (int mi = 0; mi < 4; ++mi) {
      const uint8_t* rp = &As[(wm * 64 + mi * 16 + t16) * 128];
      i32x8 am = cat8(*(const i32x4*)(rp + co0), *(const i32x4*)(rp + (co0 ^ 16)));
#pragma unroll
      for (int ni = 0; ni < 8; ++ni)
        acc[mi][ni] = __builtin_amdgcn_mfma_scale_f32_16x16x128_f8f6f4(
            am, bf[ni], acc[mi][ni], 0, 0, 0, SC1, 0, SC1);
    }
    __builtin_amdgcn_s_setprio(0);
    asm volatile("s_barrier" ::: "memory");
    if (t + 2 < G1NT) STAGE(t & 1, t + 2);
  }

  // ---- epilogue: e = exp(acc/64) -> fp8 P-tile in LDS; den += rowsum ----
  float rsum[4][4];
#pragma unroll
  for (int mi = 0; mi < 4; ++mi)
#pragma unroll
    for (int r = 0; r < 4; ++r) rsum[mi][r] = 0.f;
#pragma unroll
  for (int mi = 0; mi < 4; ++mi) {
    int rloc = wm * 64 + mi * 16 + quad * 4;
#pragma unroll
    for (int ni = 0; ni < 8; ++ni) {
      int cloc = wn * 128 + ni * 16 + t16;
#pragma unroll
      for (int r = 0; r < 4; ++r) {
        float e = __expf(acc[mi][ni][r] * 0.015625f);   // undo K x64 scale
        smem[(rloc + r) * PS1 + cloc] = (uint8_t)pk8(e, e);
        rsum[mi][r] += e;
      }
    }
  }
#pragma unroll
  for (int mi = 0; mi < 4; ++mi)
#pragma unroll
    for (int r = 0; r < 4; ++r) {
      float s = rsum[mi][r];
      s += __shfl_xor(s, 1);
      s += __shfl_xor(s, 2);
      s += __shfl_xor(s, 4);
      s += __shfl_xor(s, 8);
      if (t16 == 0)
        atomicAdd(&den[mBase + wm * 64 + mi * 16 + quad * 4 + r], s);
    }
  __syncthreads();
  // coalesced NT store: 8 x 512thr x 16B = 64KB fp8 tile (256 x 256)
  int rr  = tid >> 4;            // 0..31
  int c16 = (tid & 15) * 16;     // 0..240
#pragma unroll
  for (int i = 0; i < 8; ++i) {
    int row = i * 32 + rr;
    i32x4 v = *(const i32x4*)&smem[row * PS1 + c16];
    __builtin_nontemporal_store(v, (i32x4*)&Pout[(size_t)(mBase + row) * VOCAB + nBase + c16]);
  }
}

// ---------------------------------------------------------------------------
// GEMM2: num[m][d] = P @ K, M=4096 N=1024 K=32000. Same 256x256 / 64x128-wave
// structure, __launch_bounds__(512,1) (VGPR ~220, no spill).
// z=4 K-split, GRID = 256 EXACTLY (1 block/CU, 128KB LDS; round-6's 320-block
// grid had a 64-block tail at 62% utilization). Uneven slices 63/63/62/62
// K-steps (sum=250). XCD mapping: x=bid&7 -> dt=x&3, zhalf=x>>2; g=bid>>3 ->
// mt=g&15, zsub=g>>4; zz=zhalf*2+zsub. Each XCD: fixed dt + zhalf -> its
// 4MB KT window stays L2-resident; P streams via L3.
// Slices: z1->s1 plain, z3->s2 plain, z0/z2->s0 atomicAdd (16MB memset).
__global__ __launch_bounds__(512, 1) void k_g2(
    const uint8_t* __restrict__ P, const uint8_t* __restrict__ KT,
    float* __restrict__ s0, float* __restrict__ s1, float* __restrict__ s2)
{
  __shared__ uint8_t smem[131072];      // 2 slots x (A 32KB + B 32KB)

  int tid  = threadIdx.x;
  int wave = tid >> 6;
  int lane = tid & 63;
  int quad = lane >> 4;
  int t16  = lane & 15;
  int wm = wave >> 1;                   // 0..3 (M)
  int wn = wave & 1;                    // 0..1 (D)

  int bid = blockIdx.x;
  int x   = bid & 7;                    // XCD (round-robin dispatch)
  int g   = bid >> 3;                   // 0..31
  int dt  = x & 3;                      // 0..3  d-tile (256 cols)
  int zz  = (x >> 2) * 2 + (g >> 4);    // 0..3  K-slice
  int mt  = g & 15;                     // 0..15 m-tile (256 rows)
  long mBase = (long)mt * 256;
  long dBase = (long)dt * 256;
  int  nsteps = (zz < 2) ? 63 : 62;                        // 63+63+62+62 = 250
  long k0 = ((long)zz * 62 + (zz < 2 ? zz : 2)) * 128;     // 0,8064,16128,24064

  const uint8_t* Ab = P  + (size_t)mBase * VOCAB + k0;
  const uint8_t* Bb = KT + (size_t)dBase * VOCAB + k0;
  int lrow = lane >> 3;
  int lcol = ((lane & 7) ^ lrow) * 16;

  f32x4 acc[4][8];
#pragma unroll
  for (int i = 0; i < 4; ++i)
#pragma unroll
    for (int j = 0; j < 8; ++j) acc[i][j] = (f32x4){0.f, 0.f, 0.f, 0.f};

  int sw  = t16 & 7;
  int co0 = (((quad << 1) ^ sw) << 4);
  const int SC1 = 0x7F7F7F7F;

  auto STAGE = [&](int slot, int t) {
    uint8_t* As = &smem[slot * 65536];
    uint8_t* Bs = As + 32768;
    long kk = (long)t * 128;
#pragma unroll
    for (int gi = 0; gi < 4; ++gi) {
      int r0 = wave * 32 + gi * 8;
      gload_lds16(Ab + (size_t)(r0 + lrow) * VOCAB + kk + lcol, As + r0 * 128);
    }
#pragma unroll
    for (int gi = 0; gi < 4; ++gi) {
      int r0 = wave * 32 + gi * 8;
      gload_lds16(Bb + (size_t)(r0 + lrow) * VOCAB + kk + lcol, Bs + r0 * 128);
    }
  };

  STAGE(0, 0);
  STAGE(1, 1);                          // 16 loads in flight per wave

  for (int t = 0; t < nsteps; ++t) {
    if (t + 1 < nsteps)
      asm volatile("s_waitcnt vmcnt(8)\n\ts_barrier" ::: "memory");
    else
      asm volatile("s_waitcnt vmcnt(0)\n\ts_barrier" ::: "memory");

    const uint8_t* As = &smem[(t & 1) * 65536];
    const uint8_t* Bs = As + 32768;

    i32x8 bf[8];
#pragma unroll
    for (int ni = 0; ni < 8; ++ni) {
      const uint8_t* rp = &Bs[(wn * 128 + ni * 16 + t16) * 128];
      bf[ni] = cat8(*(const i32x4*)(rp + co0), *(const i32x4*)(rp + (co0 ^ 16)));
    }
    __builtin_amdgcn_s_setprio(1);
#pragma unroll
    for (int mi = 0; mi < 4; ++mi) {
      const uint8_t* rp = &As[(wm * 64 + mi * 16 + t16) * 128];
      i32x8 am = cat8(*(const i32x4*)(rp + co0), *(const i32x4*)(rp + (co0 ^ 16)));
#pragma unroll
      for (int ni = 0; ni < 8; ++ni)
        acc[mi][ni] = __builtin_amdgcn_mfma_scale_f32_16x16x128_f8f6f4(
            am, bf[ni], acc[mi][ni], 0, 0, 0, SC1, 0, SC1);
    }
    __builtin_amdgcn_s_setprio(0);
    asm volatile("s_barrier" ::: "memory");
    if (t + 2 < nsteps) STAGE(t & 1, t + 2);
  }

  // epilogue: z1/z3 plain-store their private slice; z0/z2 share s0 via atomics
  float* outp = (zz == 1) ? s1 : (zz == 3) ? s2 : s0;
  bool plain = (zz == 1) || (zz == 3);
#pragma unroll
  for (int mi = 0; mi < 4; ++mi) {
    long row = mBase + wm * 64 + mi * 16 + quad * 4;
#pragma unroll
    for (int ni = 0; ni < 8; ++ni) {
      long col = dBase + wn * 128 + ni * 16 + t16;
#pragma unroll
      for (int r = 0; r < 4; ++r) {
        float* p = &outp[(size_t)(row + r) * D_DIM + col];
        if (plain) *p = acc[mi][ni][r];
        else       atomicAdd(p, acc[mi][ni][r]);
      }
    }
  }
}

// ---------------------------------------------------------------------------
// bf16 GEMM for GEMM3 only: Cout = A@B^T + bias[col] + resid (128x128 tile, BK=64)
__global__ __launch_bounds__(256) void k_gemm_bf(
    const short* __restrict__ A, int lda,
    const short* __restrict__ B, int ldb, int Kdim,
    const float* __restrict__ bias, const float* __restrict__ resid,
    float* __restrict__ Cout)
{
  __shared__ short smem[16384];
  short* As = smem;
  short* Bs = smem + 8192;

  int tid  = threadIdx.x;
  int wave = tid >> 6;
  int lane = tid & 63;
  int quad = lane >> 4;
  int t16  = lane & 15;
  int wy = wave >> 1, wx = wave & 1;

  long mBase = (long)blockIdx.y * 128;
  long nBase = (long)blockIdx.x * 128;

  const short* Ab = A + (size_t)mBase * lda;
  const short* Bb = B + (size_t)nBase * ldb;
  int lrow = lane >> 3;
  int lcol = ((lane & 7) ^ lrow) * 8;

  f32x4 acc[4][4];
#pragma unroll
  for (int i = 0; i < 4; ++i)
#pragma unroll
    for (int j = 0; j < 4; ++j) acc[i][j] = (f32x4){0.f, 0.f, 0.f, 0.f};

  int sw = t16 & 7;

  for (int kk = 0; kk < Kdim; kk += 64) {
#pragma unroll
    for (int i = 0; i < 4; ++i) {
      int row = wave * 32 + i * 8;
      gload_lds16(Ab + (size_t)(row + lrow) * lda + kk + lcol, &As[row * 64]);
      gload_lds16(Bb + (size_t)(row + lrow) * ldb + kk + lcol, &Bs[row * 64]);
    }
    __syncthreads();
#pragma unroll
    for (int kc = 0; kc < 8; kc += 4) {
      bf16x8 af[4], bfr[4];
#pragma unroll
      for (int mi = 0; mi < 4; ++mi)
        af[mi] = *(const bf16x8*)&As[(wy * 64 + mi * 16 + t16) * 64 +
                                     (((kc + quad) ^ sw) << 3)];
#pragma unroll
      for (int ni = 0; ni < 4; ++ni)
        bfr[ni] = *(const bf16x8*)&Bs[(wx * 64 + ni * 16 + t16) * 64 +
                                      (((kc + quad) ^ sw) << 3)];
#pragma unroll
      for (int mi = 0; mi < 4; ++mi)
#pragma unroll
        for (int ni = 0; ni < 4; ++ni)
          acc[mi][ni] = __builtin_amdgcn_mfma_f32_16x16x32_bf16(af[mi], bfr[ni],
                                                                acc[mi][ni], 0, 0, 0);
    }
    __syncthreads();
  }

#pragma unroll
  for (int mi = 0; mi < 4; ++mi) {
    long row = mBase + wy * 64 + mi * 16 + quad * 4;
#pragma unroll
    for (int ni = 0; ni < 4; ++ni) {
      long col = nBase + wx * 64 + ni * 16 + t16;
#pragma unroll
      for (int r = 0; r < 4; ++r) {
        size_t idx = (size_t)(row + r) * 1024 + col;
        Cout[idx] = acc[mi][ni][r] + bias[col] + resid[idx];
      }
    }
  }
}

// ---------------------------------------------------------------------------
// reprog_bf16 = bf16((s0+s1+s2) / (64*den[row]))  (undo K x64 scale, sum slices)
__global__ void k_div(const float* __restrict__ s0, const float* __restrict__ s1,
                      const float* __restrict__ s2,
                      const float* __restrict__ den, short* __restrict__ out) {
  int i = (blockIdx.x * 256 + threadIdx.x) * 4;
  float4 a = *(const float4*)(s0 + i);
  float4 b = *(const float4*)(s1 + i);
  float4 c = *(const float4*)(s2 + i);
  float inv = 0.015625f / den[i >> 10];
  ushort4 u;
  u.x = f2bf((a.x + b.x + c.x) * inv); u.y = f2bf((a.y + b.y + c.y) * inv);
  u.z = f2bf((a.z + b.z + c.z) * inv); u.w = f2bf((a.w + b.w + c.w) * inv);
  *(ushort4*)(out + i) = u;
}

// ---------------------------------------------------------------------------
// per-row LayerNorm over 1024 cols; one block (256 thr) per row
__global__ __launch_bounds__(256) void k_ln(const float* __restrict__ x,
                                            const float* __restrict__ gamma,
                                            const float* __restrict__ beta,
                                            float* __restrict__ out) {
  __shared__ float s_sum[4], s_sq[4];
  int row = blockIdx.x;
  int tid = threadIdx.x;
  const float* xr = x + (size_t)row * 1024;
  float4 v = *(const float4*)(xr + tid * 4);
  float s = v.x + v.y + v.z + v.w;
  float q = v.x * v.x + v.y * v.y + v.z * v.z + v.w * v.w;
#pragma unroll
  for (int off = 32; off >= 1; off >>= 1) {
    s += __shfl_down(s, off);
    q += __shfl_down(q, off);
  }
  int wv = tid >> 6;
  if ((tid & 63) == 0) { s_sum[wv] = s; s_sq[wv] = q; }
  __syncthreads();
  float tot  = s_sum[0] + s_sum[1] + s_sum[2] + s_sum[3];
  float totq = s_sq[0] + s_sq[1] + s_sq[2] + s_sq[3];
  float mu   = tot * (1.0f / 1024.0f);
  float var  = totq * (1.0f / 1024.0f) - mu * mu;
  float rstd = rsqrtf(var + 1e-5f);
  float4 g = *(const float4*)(gamma + tid * 4);
  float4 b = *(const float4*)(beta + tid * 4);
  float4 o;
  o.x = (v.x - mu) * rstd * g.x + b.x;
  o.y = (v.y - mu) * rstd * g.y + b.y;
  o.z = (v.z - mu) * rstd * g.z + b.z;
  o.w = (v.w - mu) * rstd * g.w + b.w;
  *(float4*)(out + (size_t)row * 1024 + tid * 4) = o;
}

// ---------------------------------------------------------------------------
extern "C" void kernel_launch(void* const* d_in, const int* in_sizes, int n_in,
                              void* d_out, int out_size, void* d_ws, size_t ws_size,
                              hipStream_t stream) {
  const float* patch = (const float*)d_in[0];   // [4096,1024]
  const float* proto = (const float*)d_in[1];   // [32000,1024]
  const float* W     = (const float*)d_in[2];   // [1024,1024]
  const float* bvec  = (const float*)d_in[3];
  const float* gamma = (const float*)d_in[4];
  const float* beta  = (const float*)d_in[5];
  float* out = (float*)d_out;

  char* ws = (char*)d_ws;
  size_t off = 0;
  uint8_t* Q8  = (uint8_t*)(ws + off); off += (size_t)ROWS * D_DIM;      //   4 MB fp8 Q
  uint8_t* Kb8 = (uint8_t*)(ws + off); off += (size_t)VOCAB * D_DIM;     //  31.25 MB fp8 K (x64)
  uint8_t* KT8 = (uint8_t*)(ws + off); off += (size_t)VOCAB * D_DIM;     //  31.25 MB fp8 K^T (x64)
  short*   Wb  = (short*)(ws + off);   off += (size_t)D_DIM * D_DIM * 2; //   2 MB bf16 W
  short*   Rb  = (short*)(ws + off);   off += (size_t)ROWS * D_DIM * 2;  //   8 MB bf16 reprog
  uint8_t* P8  = (uint8_t*)(ws + off); off += (size_t)ROWS * VOCAB;      // 131 MB fp8 P
  float*   num = (float*)(ws + off);   off += (size_t)ROWS * D_DIM * 4;  //  16 MB fp32
  float*   den = (float*)(ws + off);   off += (size_t)ROWS * 4;          //  16 KB fp32 den
  float*   pre = (float*)P8;    // reuse P region for pre-LN buffer (k_g2 done reading)
  // GEMM2 z=4 split slices: s0 @ ws+0 (16MB over Q8+Kb8-head, atomicAdd by
  // z0+z2, memset AFTER g1), s1 @ ws+16MB (Kb8 tail, ends 32MB < 35.25MB KT8
  // start; plain-stored by z1), s2 = num (plain-stored by z3).
  float*   sz0 = (float*)(ws);
  float*   sz1 = (float*)(ws + (size_t)16 * 1024 * 1024);
  float*   sz2 = num;

  hipMemsetAsync(den, 0, ROWS * sizeof(float), stream);

  k_cvt_q8<<<ROWS * D_DIM / 8 / 256, 256, 0, stream>>>(patch, Q8);
  k_cvt<<<D_DIM * D_DIM / 4 / 256, 256, 0, stream>>>(W, Wb, D_DIM * D_DIM / 4);
  k_prep_K8<<<dim3(VOCAB / 64, D_DIM / 64), 256, 0, stream>>>(proto, Kb8, KT8, VOCAB, D_DIM);

  // GEMM1: P = exp(Q @ K^T), den += rowsum — 256x256 tile, 64x128/wave
  k_g1<<<2000, 512, 0, stream>>>(Q8, Kb8, P8, den);

  // zero the z0/z2 atomic slice (overwrites Q8/Kb8-head — AFTER g1 on-stream)
  hipMemsetAsync(sz0, 0, (size_t)16 * 1024 * 1024, stream);

  // GEMM2: P @ K — 256x256 tile, z=4, grid 256 (1 block/CU, no tail)
  k_g2<<<256, 512, 0, stream>>>(P8, KT8, sz0, sz1, sz2);

  k_div<<<ROWS * D_DIM / 4 / 256, 256, 0, stream>>>(sz0, sz1, sz2, den, Rb);

  // GEMM3: pre = reprog @ W^T + b + patch — M=4096 N=1024 K=1024 (bf16)
  k_gemm_bf<<<dim3(D_DIM / 128, ROWS / 128), 256, 0, stream>>>(
      Rb, D_DIM, Wb, D_DIM, D_DIM, bvec, patch, pre);

  k_ln<<<ROWS, 256, 0, stream>>>(pre, gamma, beta, out);
}

// Round 8
// 632.587 us; speedup vs baseline: 1.3629x; 1.1432x over previous
//
#include <hip/hip_runtime.h>
#include <hip/hip_bf16.h>
#include <cstdint>
#include <cstddef>

#define D_DIM 1024
#define VOCAB 32000
#define ROWS  4096      // 16*256

typedef __attribute__((ext_vector_type(8))) short bf16x8;   // 8 bf16 (MFMA A/B frag)
typedef __attribute__((ext_vector_type(4))) float f32x4;    // MFMA C/D frag
typedef __attribute__((ext_vector_type(4))) int   i32x4;    // 16B LDS/global move
typedef __attribute__((ext_vector_type(8))) int   i32x8;    // fp8 K=128 A/B frag (8 VGPRs)

static __device__ __forceinline__ i32x8 cat8(i32x4 lo, i32x4 hi) {
  return __builtin_shufflevector(lo, hi, 0, 1, 2, 3, 4, 5, 6, 7);
}

// float -> bf16 bits, round-to-nearest-even
static __device__ __forceinline__ unsigned short f2bf(float f) {
  union { float f; unsigned int u; } c; c.f = f;
  unsigned int u = c.u;
  u += 0x7fffu + ((u >> 16) & 1u);
  return (unsigned short)(u >> 16);
}

// pack two floats -> two fp8 e4m3 bytes (low 16 bits of result)
static __device__ __forceinline__ int pk8(float a, float b) {
  return __builtin_amdgcn_cvt_pk_fp8_f32(a, b, 0, false);
}

// async global->LDS, 16B per lane. LDS base wave-uniform; data lands at base + lane*16.
static __device__ __forceinline__ void gload_lds16(const void* g, void* s) {
  __builtin_amdgcn_global_load_lds(
      (const __attribute__((address_space(1))) uint32_t*)(g),
      (__attribute__((address_space(3))) uint32_t*)(s), 16, 0, 0);
}

// ---------------------------------------------------------------------------
// fp32 -> bf16 convert (4 elems/thread) — used for W only
__global__ void k_cvt(const float* __restrict__ src, short* __restrict__ dst, int n4) {
  int i = blockIdx.x * 256 + threadIdx.x;
  if (i < n4) {
    float4 v = *(const float4*)(src + (size_t)i * 4);
    ushort4 u;
    u.x = f2bf(v.x); u.y = f2bf(v.y); u.z = f2bf(v.z); u.w = f2bf(v.w);
    *(ushort4*)(dst + (size_t)i * 4) = u;
  }
}

// ---------------------------------------------------------------------------
// patch fp32 -> Q fp8 e4m3 (unscaled; |patch| ~ N(0,1) fits), 8 elems/thread
__global__ void k_cvt_q8(const float* __restrict__ src, uint8_t* __restrict__ dst) {
  int i = blockIdx.x * 256 + threadIdx.x;
  float4 a = *(const float4*)(src + (size_t)i * 8);
  float4 b = *(const float4*)(src + (size_t)i * 8 + 4);
  uint2 o;
  o.x = (pk8(a.x, a.y) & 0xffff) | (pk8(a.z, a.w) << 16);
  o.y = (pk8(b.x, b.y) & 0xffff) | (pk8(b.z, b.w) << 16);
  *(uint2*)(dst + (size_t)i * 8) = o;
}

// ---------------------------------------------------------------------------
// fused: proto fp32 [R][C] -> Kb fp8 [R][C] (x64) AND KT fp8 [C][R] (x64), one read
__global__ void k_prep_K8(const float* __restrict__ src, uint8_t* __restrict__ kb,
                          uint8_t* __restrict__ kt, int R, int C) {
  __shared__ uint8_t tile[64][68];
  int t  = threadIdx.x;           // 0..255
  int r0 = blockIdx.x * 64;       // v block
  int c0 = blockIdx.y * 64;       // d block
  int lr = t >> 4;                // 0..15
  int lc = (t & 15) * 4;          // 0..60
#pragma unroll
  for (int i = 0; i < 4; ++i) {
    int r = lr + 16 * i;
    float4 v = *(const float4*)(src + (size_t)(r0 + r) * C + c0 + lc);
    unsigned p = (pk8(v.x * 64.f, v.y * 64.f) & 0xffff) | (pk8(v.z * 64.f, v.w * 64.f) << 16);
    *(unsigned*)&tile[r][lc] = p;
    *(unsigned*)(kb + (size_t)(r0 + r) * C + c0 + lc) = p;
  }
  __syncthreads();
#pragma unroll
  for (int i = 0; i < 4; ++i) {
    int c = lr + 16 * i;          // d within tile
    unsigned p = tile[lc + 0][c] | (tile[lc + 1][c] << 8) |
                 (tile[lc + 2][c] << 16) | ((unsigned)tile[lc + 3][c] << 24);
    *(unsigned*)(kt + (size_t)(c0 + c) * R + r0 + lc) = p;
  }
}

// ---------------------------------------------------------------------------
// GEMM1: P = exp(Q @ K^T) (x64 scale), den += rowsum.
// M=4096 N=32000 K=1024, fp8 MX. 256(m) x 256(n) tile, 512 thr = 8 waves
// (4M x 2N), 64x128 per wave: 24 ds_read_b128 feed 32 MFMAs per K-step
// (validated round-7: bank-conflict cycles -24% vs 64x64 structure).
// ROUND-8 SPILL FIX (round 6/7: WRITE +280MB scratch, VGPR capped 128):
//   (a) hold am[4] (32 regs), STREAM bf per-ni (8+8 in flight) -> peak arch
//       pressure ~80 (was ~170 when bf[8]=64 held + 16 batched ds_reads);
//   (b) amdgpu_waves_per_eu(2): budget 512/2 = 256 unified (the 128KB-LDS
//       config runs at 2 waves/SIMD anyway -> zero occupancy cost).
// 2-slot ring, counted vmcnt(8): { vmcnt(8)+barrier; reads+MFMA; barrier;
// STAGE(t+2) }. Grid 2000 = 8 x 250 XCD-chunked. P stored NON-TEMPORAL.
#define PS1 272    // P-tile LDS row stride, bytes (16B-aligned, 256+16)
#define G1NT 8     // 1024/128 K-steps
__global__ __launch_bounds__(512)
__attribute__((amdgpu_waves_per_eu(2)))
void k_g1(
    const uint8_t* __restrict__ A,      // Q8 [4096][1024]
    const uint8_t* __restrict__ B,      // Kb8 [32000][1024]
    uint8_t* __restrict__ Pout, float* __restrict__ den)
{
  __shared__ uint8_t smem[131072];      // 2 slots x (A 32KB + B 32KB)

  int tid  = threadIdx.x;
  int wave = tid >> 6;                  // 0..7
  int lane = tid & 63;
  int quad = lane >> 4;
  int t16  = lane & 15;
  int wm = wave >> 1;                   // 0..3 (M, 64 rows each)
  int wn = wave & 1;                    // 0..1 (N, 128 cols each)

  int swz = (blockIdx.x & 7) * 250 + (blockIdx.x >> 3);  // bijective, 2000=8*250
  int nt  = swz >> 4;                   // 0..124  n-tile (256 vocab cols)
  int mt  = swz & 15;                   // 0..15   m-tile (256 rows)
  long mBase = (long)mt * 256;
  long nBase = (long)nt * 256;

  const uint8_t* Ab = A + (size_t)mBase * D_DIM;
  const uint8_t* Bb = B + (size_t)nBase * D_DIM;
  int lrow = lane >> 3;                      // 0..7
  int lcol = ((lane & 7) ^ lrow) * 16;       // swizzled source 16B chunk (bytes)

  f32x4 acc[4][8];
#pragma unroll
  for (int i = 0; i < 4; ++i)
#pragma unroll
    for (int j = 0; j < 8; ++j) acc[i][j] = (f32x4){0.f, 0.f, 0.f, 0.f};

  int sw  = t16 & 7;
  int co0 = (((quad << 1) ^ sw) << 4);
  const int SC1 = 0x7F7F7F7F;                // identity E8M0 scales

  // stage K-step t into slot: A 32KB + B 32KB, 4+4 gloads/wave (vmcnt unit: 8)
  auto STAGE = [&](int slot, int t) {
    uint8_t* As = &smem[slot * 65536];
    uint8_t* Bs = As + 32768;
    int kk = t * 128;
#pragma unroll
    for (int g = 0; g < 4; ++g) {
      int r0 = wave * 32 + g * 8;
      gload_lds16(Ab + (size_t)(r0 + lrow) * D_DIM + kk + lcol, As + r0 * 128);
    }
#pragma unroll
    for (int g = 0; g < 4; ++g) {
      int r0 = wave * 32 + g * 8;
      gload_lds16(Bb + (size_t)(r0 + lrow) * D_DIM + kk + lcol, Bs + r0 * 128);
    }
  };

  STAGE(0, 0);
  STAGE(1, 1);                          // 16 loads in flight per wave

  for (int t = 0; t < G1NT; ++t) {
    if (t + 1 < G1NT)
      asm volatile("s_waitcnt vmcnt(8)\n\ts_barrier" ::: "memory");
    else
      asm volatile("s_waitcnt vmcnt(0)\n\ts_barrier" ::: "memory");

    const uint8_t* As = &smem[(t & 1) * 65536];
    const uint8_t* Bs = As + 32768;

    // hold A frags (32 regs), stream B frags one at a time (low arch pressure)
    i32x8 am[4];
#pragma unroll
    for (int mi = 0; mi < 4; ++mi) {
      const uint8_t* rp = &As[(wm * 64 + mi * 16 + t16) * 128];
      am[mi] = cat8(*(const i32x4*)(rp + co0), *(const i32x4*)(rp + (co0 ^ 16)));
    }
    __builtin_amdgcn_s_setprio(1);
#pragma unroll
    for (int ni = 0; ni < 8; ++ni) {
      const uint8_t* rp = &Bs[(wn * 128 + ni * 16 + t16) * 128];
      i32x8 bfr = cat8(*(const i32x4*)(rp + co0), *(const i32x4*)(rp + (co0 ^ 16)));
#pragma unroll
      for (int mi = 0; mi < 4; ++mi)
        acc[mi][ni] = __builtin_amdgcn_mfma_scale_f32_16x16x128_f8f6f4(
            am[mi], bfr, acc[mi][ni], 0, 0, 0, SC1, 0, SC1);
    }
    __builtin_amdgcn_s_setprio(0);
    asm volatile("s_barrier" ::: "memory");
    if (t + 2 < G1NT) STAGE(t & 1, t + 2);
  }

  // ---- epilogue: e = exp(acc/64) -> fp8 P-tile in LDS; den += rowsum ----
  float rsum[4][4];
#pragma unroll
  for (int mi = 0; mi < 4; ++mi)
#pragma unroll
    for (int r = 0; r < 4; ++r) rsum[mi][r] = 0.f;
#pragma unroll
  for (int mi = 0; mi < 4; ++mi) {
    int rloc = wm * 64 + mi * 16 + quad * 4;
#pragma unroll
    for (int ni = 0; ni < 8; ++ni) {
      int cloc = wn * 128 + ni * 16 + t16;
#pragma unroll
      for (int r = 0; r < 4; ++r) {
        float e = __expf(acc[mi][ni][r] * 0.015625f);   // undo K x64 scale
        smem[(rloc + r) * PS1 + cloc] = (uint8_t)pk8(e, e);
        rsum[mi][r] += e;
      }
    }
  }
#pragma unroll
  for (int mi = 0; mi < 4; ++mi)
#pragma unroll
    for (int r = 0; r < 4; ++r) {
      float s = rsum[mi][r];
      s += __shfl_xor(s, 1);
      s += __shfl_xor(s, 2);
      s += __shfl_xor(s, 4);
      s += __shfl_xor(s, 8);
      if (t16 == 0)
        atomicAdd(&den[mBase + wm * 64 + mi * 16 + quad * 4 + r], s);
    }
  __syncthreads();
  // coalesced NT store: 8 x 512thr x 16B = 64KB fp8 tile (256 x 256)
  int rr  = tid >> 4;            // 0..31
  int c16 = (tid & 15) * 16;     // 0..240
#pragma unroll
  for (int i = 0; i < 8; ++i) {
    int row = i * 32 + rr;
    i32x4 v = *(const i32x4*)&smem[row * PS1 + c16];
    __builtin_nontemporal_store(v, (i32x4*)&Pout[(size_t)(mBase + row) * VOCAB + nBase + c16]);
  }
}

// ---------------------------------------------------------------------------
// GEMM2: num[m][d] = P @ K, M=4096 N=1024 K=32000. Same 256x256 / 64x128-wave
// structure + same round-8 spill fixes (am-hold/bf-stream, waves_per_eu(2)).
// z=4 K-split, grid = 256 exactly (1 block/CU, no tail). Uneven slices
// 63/63/62/62 K-steps. XCD mapping: x=bid&7 -> dt=x&3, zhalf=x>>2; g=bid>>3
// -> mt=g&15, zsub=g>>4; zz=zhalf*2+zsub. Each XCD: fixed dt+zhalf -> its
// 4MB KT window L2-resident; P streams via L3.
// Slices: z1->s1 plain, z3->s2 plain, z0/z2->s0 atomicAdd (16MB memset).
__global__ __launch_bounds__(512)
__attribute__((amdgpu_waves_per_eu(2)))
void k_g2(
    const uint8_t* __restrict__ P, const uint8_t* __restrict__ KT,
    float* __restrict__ s0, float* __restrict__ s1, float* __restrict__ s2)
{
  __shared__ uint8_t smem[131072];      // 2 slots x (A 32KB + B 32KB)

  int tid  = threadIdx.x;
  int wave = tid >> 6;
  int lane = tid & 63;
  int quad = lane >> 4;
  int t16  = lane & 15;
  int wm = wave >> 1;                   // 0..3 (M)
  int wn = wave & 1;                    // 0..1 (D)

  int bid = blockIdx.x;
  int x   = bid & 7;                    // XCD (round-robin dispatch)
  int g   = bid >> 3;                   // 0..31
  int dt  = x & 3;                      // 0..3  d-tile (256 cols)
  int zz  = (x >> 2) * 2 + (g >> 4);    // 0..3  K-slice
  int mt  = g & 15;                     // 0..15 m-tile (256 rows)
  long mBase = (long)mt * 256;
  long dBase = (long)dt * 256;
  int  nsteps = (zz < 2) ? 63 : 62;                        // 63+63+62+62 = 250
  long k0 = ((long)zz * 62 + (zz < 2 ? zz : 2)) * 128;     // 0,8064,16128,24064

  const uint8_t* Ab = P  + (size_t)mBase * VOCAB + k0;
  const uint8_t* Bb = KT + (size_t)dBase * VOCAB + k0;
  int lrow = lane >> 3;
  int lcol = ((lane & 7) ^ lrow) * 16;

  f32x4 acc[4][8];
#pragma unroll
  for (int i = 0; i < 4; ++i)
#pragma unroll
    for (int j = 0; j < 8; ++j) acc[i][j] = (f32x4){0.f, 0.f, 0.f, 0.f};

  int sw  = t16 & 7;
  int co0 = (((quad << 1) ^ sw) << 4);
  const int SC1 = 0x7F7F7F7F;

  auto STAGE = [&](int slot, int t) {
    uint8_t* As = &smem[slot * 65536];
    uint8_t* Bs = As + 32768;
    long kk = (long)t * 128;
#pragma unroll
    for (int gi = 0; gi < 4; ++gi) {
      int r0 = wave * 32 + gi * 8;
      gload_lds16(Ab + (size_t)(r0 + lrow) * VOCAB + kk + lcol, As + r0 * 128);
    }
#pragma unroll
    for (int gi = 0; gi < 4; ++gi) {
      int r0 = wave * 32 + gi * 8;
      gload_lds16(Bb + (size_t)(r0 + lrow) * VOCAB + kk + lcol, Bs + r0 * 128);
    }
  };

  STAGE(0, 0);
  STAGE(1, 1);                          // 16 loads in flight per wave

  for (int t = 0; t < nsteps; ++t) {
    if (t + 1 < nsteps)
      asm volatile("s_waitcnt vmcnt(8)\n\ts_barrier" ::: "memory");
    else
      asm volatile("s_waitcnt vmcnt(0)\n\ts_barrier" ::: "memory");

    const uint8_t* As = &smem[(t & 1) * 65536];
    const uint8_t* Bs = As + 32768;

    i32x8 am[4];
#pragma unroll
    for (int mi = 0; mi < 4; ++mi) {
      const uint8_t* rp = &As[(wm * 64 + mi * 16 + t16) * 128];
      am[mi] = cat8(*(const i32x4*)(rp + co0), *(const i32x4*)(rp + (co0 ^ 16)));
    }
    __builtin_amdgcn_s_setprio(1);
#pragma unroll
    for (int ni = 0; ni < 8; ++ni) {
      const uint8_t* rp = &Bs[(wn * 128 + ni * 16 + t16) * 128];
      i32x8 bfr = cat8(*(const i32x4*)(rp + co0), *(const i32x4*)(rp + (co0 ^ 16)));
#pragma unroll
      for (int mi = 0; mi < 4; ++mi)
        acc[mi][ni] = __builtin_amdgcn_mfma_scale_f32_16x16x128_f8f6f4(
            am[mi], bfr, acc[mi][ni], 0, 0, 0, SC1, 0, SC1);
    }
    __builtin_amdgcn_s_setprio(0);
    asm volatile("s_barrier" ::: "memory");
    if (t + 2 < nsteps) STAGE(t & 1, t + 2);
  }

  // epilogue: z1/z3 plain-store their private slice; z0/z2 share s0 via atomics
  float* outp = (zz == 1) ? s1 : (zz == 3) ? s2 : s0;
  bool plain = (zz == 1) || (zz == 3);
#pragma unroll
  for (int mi = 0; mi < 4; ++mi) {
    long row = mBase + wm * 64 + mi * 16 + quad * 4;
#pragma unroll
    for (int ni = 0; ni < 8; ++ni) {
      long col = dBase + wn * 128 + ni * 16 + t16;
#pragma unroll
      for (int r = 0; r < 4; ++r) {
        float* p = &outp[(size_t)(row + r) * D_DIM + col];
        if (plain) *p = acc[mi][ni][r];
        else       atomicAdd(p, acc[mi][ni][r]);
      }
    }
  }
}

// ---------------------------------------------------------------------------
// bf16 GEMM for GEMM3 only: Cout = A@B^T + bias[col] + resid (128x128 tile, BK=64)
__global__ __launch_bounds__(256) void k_gemm_bf(
    const short* __restrict__ A, int lda,
    const short* __restrict__ B, int ldb, int Kdim,
    const float* __restrict__ bias, const float* __restrict__ resid,
    float* __restrict__ Cout)
{
  __shared__ short smem[16384];
  short* As = smem;
  short* Bs = smem + 8192;

  int tid  = threadIdx.x;
  int wave = tid >> 6;
  int lane = tid & 63;
  int quad = lane >> 4;
  int t16  = lane & 15;
  int wy = wave >> 1, wx = wave & 1;

  long mBase = (long)blockIdx.y * 128;
  long nBase = (long)blockIdx.x * 128;

  const short* Ab = A + (size_t)mBase * lda;
  const short* Bb = B + (size_t)nBase * ldb;
  int lrow = lane >> 3;
  int lcol = ((lane & 7) ^ lrow) * 8;

  f32x4 acc[4][4];
#pragma unroll
  for (int i = 0; i < 4; ++i)
#pragma unroll
    for (int j = 0; j < 4; ++j) acc[i][j] = (f32x4){0.f, 0.f, 0.f, 0.f};

  int sw = t16 & 7;

  for (int kk = 0; kk < Kdim; kk += 64) {
#pragma unroll
    for (int i = 0; i < 4; ++i) {
      int row = wave * 32 + i * 8;
      gload_lds16(Ab + (size_t)(row + lrow) * lda + kk + lcol, &As[row * 64]);
      gload_lds16(Bb + (size_t)(row + lrow) * ldb + kk + lcol, &Bs[row * 64]);
    }
    __syncthreads();
#pragma unroll
    for (int kc = 0; kc < 8; kc += 4) {
      bf16x8 af[4], bfr[4];
#pragma unroll
      for (int mi = 0; mi < 4; ++mi)
        af[mi] = *(const bf16x8*)&As[(wy * 64 + mi * 16 + t16) * 64 +
                                     (((kc + quad) ^ sw) << 3)];
#pragma unroll
      for (int ni = 0; ni < 4; ++ni)
        bfr[ni] = *(const bf16x8*)&Bs[(wx * 64 + ni * 16 + t16) * 64 +
                                      (((kc + quad) ^ sw) << 3)];
#pragma unroll
      for (int mi = 0; mi < 4; ++mi)
#pragma unroll
        for (int ni = 0; ni < 4; ++ni)
          acc[mi][ni] = __builtin_amdgcn_mfma_f32_16x16x32_bf16(af[mi], bfr[ni],
                                                                acc[mi][ni], 0, 0, 0);
    }
    __syncthreads();
  }

#pragma unroll
  for (int mi = 0; mi < 4; ++mi) {
    long row = mBase + wy * 64 + mi * 16 + quad * 4;
#pragma unroll
    for (int ni = 0; ni < 4; ++ni) {
      long col = nBase + wx * 64 + ni * 16 + t16;
#pragma unroll
      for (int r = 0; r < 4; ++r) {
        size_t idx = (size_t)(row + r) * 1024 + col;
        Cout[idx] = acc[mi][ni][r] + bias[col] + resid[idx];
      }
    }
  }
}

// ---------------------------------------------------------------------------
// reprog_bf16 = bf16((s0+s1+s2) / (64*den[row]))  (undo K x64 scale, sum slices)
__global__ void k_div(const float* __restrict__ s0, const float* __restrict__ s1,
                      const float* __restrict__ s2,
                      const float* __restrict__ den, short* __restrict__ out) {
  int i = (blockIdx.x * 256 + threadIdx.x) * 4;
  float4 a = *(const float4*)(s0 + i);
  float4 b = *(const float4*)(s1 + i);
  float4 c = *(const float4*)(s2 + i);
  float inv = 0.015625f / den[i >> 10];
  ushort4 u;
  u.x = f2bf((a.x + b.x + c.x) * inv); u.y = f2bf((a.y + b.y + c.y) * inv);
  u.z = f2bf((a.z + b.z + c.z) * inv); u.w = f2bf((a.w + b.w + c.w) * inv);
  *(ushort4*)(out + i) = u;
}

// ---------------------------------------------------------------------------
// per-row LayerNorm over 1024 cols; one block (256 thr) per row
__global__ __launch_bounds__(256) void k_ln(const float* __restrict__ x,
                                            const float* __restrict__ gamma,
                                            const float* __restrict__ beta,
                                            float* __restrict__ out) {
  __shared__ float s_sum[4], s_sq[4];
  int row = blockIdx.x;
  int tid = threadIdx.x;
  const float* xr = x + (size_t)row * 1024;
  float4 v = *(const float4*)(xr + tid * 4);
  float s = v.x + v.y + v.z + v.w;
  float q = v.x * v.x + v.y * v.y + v.z * v.z + v.w * v.w;
#pragma unroll
  for (int off = 32; off >= 1; off >>= 1) {
    s += __shfl_down(s, off);
    q += __shfl_down(q, off);
  }
  int wv = tid >> 6;
  if ((tid & 63) == 0) { s_sum[wv] = s; s_sq[wv] = q; }
  __syncthreads();
  float tot  = s_sum[0] + s_sum[1] + s_sum[2] + s_sum[3];
  float totq = s_sq[0] + s_sq[1] + s_sq[2] + s_sq[3];
  float mu   = tot * (1.0f / 1024.0f);
  float var  = totq * (1.0f / 1024.0f) - mu * mu;
  float rstd = rsqrtf(var + 1e-5f);
  float4 g = *(const float4*)(gamma + tid * 4);
  float4 b = *(const float4*)(beta + tid * 4);
  float4 o;
  o.x = (v.x - mu) * rstd * g.x + b.x;
  o.y = (v.y - mu) * rstd * g.y + b.y;
  o.z = (v.z - mu) * rstd * g.z + b.z;
  o.w = (v.w - mu) * rstd * g.w + b.w;
  *(float4*)(out + (size_t)row * 1024 + tid * 4) = o;
}

// ---------------------------------------------------------------------------
extern "C" void kernel_launch(void* const* d_in, const int* in_sizes, int n_in,
                              void* d_out, int out_size, void* d_ws, size_t ws_size,
                              hipStream_t stream) {
  const float* patch = (const float*)d_in[0];   // [4096,1024]
  const float* proto = (const float*)d_in[1];   // [32000,1024]
  const float* W     = (const float*)d_in[2];   // [1024,1024]
  const float* bvec  = (const float*)d_in[3];
  const float* gamma = (const float*)d_in[4];
  const float* beta  = (const float*)d_in[5];
  float* out = (float*)d_out;

  char* ws = (char*)d_ws;
  size_t off = 0;
  uint8_t* Q8  = (uint8_t*)(ws + off); off += (size_t)ROWS * D_DIM;      //   4 MB fp8 Q
  uint8_t* Kb8 = (uint8_t*)(ws + off); off += (size_t)VOCAB * D_DIM;     //  31.25 MB fp8 K (x64)
  uint8_t* KT8 = (uint8_t*)(ws + off); off += (size_t)VOCAB * D_DIM;     //  31.25 MB fp8 K^T (x64)
  short*   Wb  = (short*)(ws + off);   off += (size_t)D_DIM * D_DIM * 2; //   2 MB bf16 W
  short*   Rb  = (short*)(ws + off);   off += (size_t)ROWS * D_DIM * 2;  //   8 MB bf16 reprog
  uint8_t* P8  = (uint8_t*)(ws + off); off += (size_t)ROWS * VOCAB;      // 131 MB fp8 P
  float*   num = (float*)(ws + off);   off += (size_t)ROWS * D_DIM * 4;  //  16 MB fp32
  float*   den = (float*)(ws + off);   off += (size_t)ROWS * 4;          //  16 KB fp32 den
  float*   pre = (float*)P8;    // reuse P region for pre-LN buffer (k_g2 done reading)
  // GEMM2 z=4 split slices: s0 @ ws+0 (16MB over Q8+Kb8-head, atomicAdd by
  // z0+z2, memset AFTER g1), s1 @ ws+16MB (Kb8 tail, ends 32MB < 35.25MB KT8
  // start; plain-stored by z1), s2 = num (plain-stored by z3).
  float*   sz0 = (float*)(ws);
  float*   sz1 = (float*)(ws + (size_t)16 * 1024 * 1024);
  float*   sz2 = num;

  hipMemsetAsync(den, 0, ROWS * sizeof(float), stream);

  k_cvt_q8<<<ROWS * D_DIM / 8 / 256, 256, 0, stream>>>(patch, Q8);
  k_cvt<<<D_DIM * D_DIM / 4 / 256, 256, 0, stream>>>(W, Wb, D_DIM * D_DIM / 4);
  k_prep_K8<<<dim3(VOCAB / 64, D_DIM / 64), 256, 0, stream>>>(proto, Kb8, KT8, VOCAB, D_DIM);

  // GEMM1: P = exp(Q @ K^T), den += rowsum — 256x256 tile, 64x128/wave
  k_g1<<<2000, 512, 0, stream>>>(Q8, Kb8, P8, den);

  // zero the z0/z2 atomic slice (overwrites Q8/Kb8-head — AFTER g1 on-stream)
  hipMemsetAsync(sz0, 0, (size_t)16 * 1024 * 1024, stream);

  // GEMM2: P @ K — 256x256 tile, z=4, grid 256 (1 block/CU, no tail)
  k_g2<<<256, 512, 0, stream>>>(P8, KT8, sz0, sz1, sz2);

  k_div<<<ROWS * D_DIM / 4 / 256, 256, 0, stream>>>(sz0, sz1, sz2, den, Rb);

  // GEMM3: pre = reprog @ W^T + b + patch — M=4096 N=1024 K=1024 (bf16)
  k_gemm_bf<<<dim3(D_DIM / 128, ROWS / 128), 256, 0, stream>>>(
      Rb, D_DIM, Wb, D_DIM, D_DIM, bvec, patch, pre);

  k_ln<<<ROWS, 256, 0, stream>>>(pre, gamma, beta, out);
}